// Round 17
// baseline (4277.542 us; speedup 1.0000x reference)
//
#include <hip/hip_runtime.h>

typedef __bf16 bf16x8 __attribute__((ext_vector_type(8)));
typedef float f32x4 __attribute__((ext_vector_type(4)));
typedef unsigned short u16;
typedef unsigned long long u64;

#define NSTEP 512

#define AL(p)   __hip_atomic_load((p), __ATOMIC_RELAXED, __HIP_MEMORY_SCOPE_AGENT)
#define AS(p,v) __hip_atomic_store((p), (v), __ATOMIC_RELAXED, __HIP_MEMORY_SCOPE_AGENT)

__device__ __forceinline__ u16 f2bf(float f) {
  union { float f; unsigned u; } x; x.f = f;
  return (u16)((x.u + 0x7fffu + ((x.u >> 16) & 1u)) >> 16);
}

// zero h buffer 0 + 1024 per-wave epoch flags (every call -> deterministic replays)
__global__ void prep_kernel(u64* __restrict__ H0, int* __restrict__ F) {
  int i = blockIdx.x * blockDim.x + threadIdx.x;
  if (i < 16384) AS(H0 + i, 0ULL);
  if (i < 32768) AS(&F[i], 0);
}

// A1[t*64+b][512] bf16 embedding gather
__global__ void gather_kernel(const int* __restrict__ sent, const float* __restrict__ emb,
                              u16* __restrict__ A1) {
  int row = blockIdx.x * 4 + (threadIdx.x >> 6);   // t*64+b
  int lane = threadIdx.x & 63;
  int t = row >> 6, b = row & 63;
  int idx = sent[b * 512 + t];
  const float* src = emb + (size_t)idx * 512 + lane * 8;
  u16* dst = A1 + (size_t)row * 512 + lane * 8;
  #pragma unroll
  for (int k = 0; k < 8; ++k) dst[k] = f2bf(src[k]);
}

// 256 WGs x 256 thr. WG j owns h cols [j*4,j*4+4), gates packed rb = g*4+nn = lr.
// Weights in padded LDS. h: per-step FRESH buffers (never reused) — producers
// store sc1 (straight to L3), consumers read CACHED after observing the
// producer's epoch flag (r12/r15-proven visibility pair). NO grid barrier (r15);
// concurrent flag-load issue (r16). NEW (r17): exponential-backoff polling
// (1 -> 8 -> 32 s_sleep units) to cut far-fabric poll congestion ~20x.
__global__ void __launch_bounds__(256, 2)
lstm_kernel(const u16* __restrict__ A1,
            const float* __restrict__ wih, const float* __restrict__ whh,
            const float* __restrict__ bih, const float* __restrict__ bhh,
            u16* __restrict__ H, float* __restrict__ out, int* __restrict__ F) {
  __shared__ u16 wlds[48 * 16 * 36];        // 55296 B, stride-36 pad
  __shared__ alignas(8) u16 hx[4][16][4];   // per-wave h-store packing bounce

  const int j   = blockIdx.x;
  const int tid = threadIdx.x;
  const int w   = tid >> 6;            // wave = batch tile 0..3
  const int l   = tid & 63;
  const int lr  = l & 15, lk = l >> 4;
  const int g   = lr >> 2, nn = lr & 3;
  const int wrow = g * 1024 + j * 4 + nn;

  // ---- stage ALL weights fp32->bf16 into padded LDS (once) ----
  for (int task = tid; task < 3072; task += 256) {
    int kk = task >> 6;                 // K chunk of 32 (0..47)
    int rem = task & 63;
    int rb = rem >> 2, q = rem & 3;
    int row = (rb >> 2) * 1024 + j * 4 + (rb & 3);
    const float* src = (kk < 16) ? (wih + (size_t)row * 512 + kk * 32 + q * 8)
                                 : (whh + (size_t)row * 1024 + (kk - 16) * 32 + q * 8);
    u16* dst = wlds + (kk * 16 + rb) * 36 + q * 8;
    #pragma unroll
    for (int e = 0; e < 8; ++e) dst[e] = f2bf(src[e]);
  }
  __syncthreads();

  const float bias = bih[wrow] + bhh[wrow];
  const float sca = (g == 2) ? 2.f : 1.f;   // tanh-as-sigmoid scaling
  const float bd  = (g == 2) ? -1.f : 0.f;
  const int arow = w * 16 + lr;             // batch row for A fragments
  const u16* bx = wlds + lr * 36 + lk * 8;  // + kk*576 per K chunk

  float cst[4] = {0.f, 0.f, 0.f, 0.f};

  // prefetch A1 fragments for t=0
  bf16x8 ax[16];
  {
    const u16* apre = A1 + (size_t)arow * 512 + lk * 8;
    #pragma unroll
    for (int kk = 0; kk < 16; ++kk) ax[kk] = *(const bf16x8*)(apre + kk * 32);
  }

  union AF { bf16x8 v; u64 q[2]; };

  // flag of (producer WG p, wave w) at F[p*128 + w*32]; lane l covers chunk c's
  // producer WG c*64+l. Exponential backoff: poll rate drops ~20x while waiting.
#define FADDR(c) (F + (((c) * 64 + l) * 128) + w * 32)
#define WAITV(vv, c)                                                        \
  { int _n = 0;                                                             \
    while (vv < t) {                                                        \
      if (_n < 2)      __builtin_amdgcn_s_sleep(1);                         \
      else if (_n < 5) __builtin_amdgcn_s_sleep(8);                         \
      else             __builtin_amdgcn_s_sleep(32);                        \
      ++_n;                                                                 \
      vv = AL(FADDR(c));                                                    \
    } }
#define LD8(BUF, CH)                                                        \
  { _Pragma("unroll")                                                       \
    for (int r = 0; r < 8; ++r)                                             \
      BUF[r].v = *(const bf16x8*)(hp + (CH) * 256 + r * 32); }
#define MM8(BUF, W0)                                                        \
  { _Pragma("unroll")                                                       \
    for (int r = 0; r < 8; ++r) {                                           \
      bf16x8 b = *(const bf16x8*)(bx + ((W0) + r) * 576);                   \
      acc = __builtin_amdgcn_mfma_f32_16x16x32_bf16(BUF[r].v, b, acc, 0, 0, 0); \
    } }

  #pragma unroll 1
  for (int t = 0; t < NSTEP; ++t) {
    AF ha[8], hb[8];
    const u16* hp = H + (size_t)t * 65536 + (size_t)arow * 1024 + lk * 8;
    // issue ALL 4 chunk-flag loads concurrently (one far RT covers them all)
    int v0 = AL(FADDR(0));
    int v1 = AL(FADDR(1));
    int v2 = AL(FADDR(2));
    int v3 = AL(FADDR(3));
    // x-projection from prefetched ax (hides the flag round trip)
    f32x4 acc = { bias, bias, bias, bias };
    #pragma unroll
    for (int kk = 0; kk < 16; ++kk) {
      bf16x8 b = *(const bf16x8*)(bx + kk * 576);
      acc = __builtin_amdgcn_mfma_f32_16x16x32_bf16(ax[kk], b, acc, 0, 0, 0);
    }
    // per-chunk readiness: register compare fast path, backoff re-poll for laggards
    WAITV(v0, 0);
    LD8(ha, 0);
    WAITV(v1, 1);
    LD8(hb, 1);
    MM8(ha, 16);
    WAITV(v2, 2);
    LD8(ha, 2);
    MM8(hb, 24);
    WAITV(v3, 3);
    LD8(hb, 3);
    MM8(ha, 32);
    MM8(hb, 40);

    // activations + state update; lanes lr<4 own (rows lk*4+r, col lr)
    float hv4[4], cn4[4];
    #pragma unroll
    for (int r = 0; r < 4; ++r) {
      float xv = acc[r];
      float act = sca / (1.f + __expf(-sca * xv)) + bd;  // sigmoid / tanh
      float gg = __shfl_xor(act, 8);
      float ff = __shfl_xor(act, 4);
      float oo = __shfl_xor(act, 12);
      float cn = ff * cst[r] + act * gg;   // act = i at lanes lr<4
      cst[r] = cn;
      float tc = 2.f / (1.f + __expf(-2.f * cn)) - 1.f;
      hv4[r] = oo * tc;
      cn4[r] = cn;
    }

    if (t == NSTEP - 1) {
      if (lr < 4) {
        #pragma unroll
        for (int r = 0; r < 4; ++r) {
          int R = w * 16 + lk * 4 + r;
          out[(size_t)R * 1024 + j * 4 + lr]          = hv4[r];
          out[65536 + (size_t)R * 1024 + j * 4 + lr]  = hv4[r];
          out[131072 + (size_t)R * 1024 + j * 4 + lr] = cn4[r];
        }
      }
    } else {
      // pack wave's 16x4 h tile in LDS (same-wave ds ops are in-order; no barrier)
      if (lr < 4) {
        #pragma unroll
        for (int r = 0; r < 4; ++r) hx[w][lk * 4 + r][lr] = f2bf(hv4[r]);
      }
      if (l < 16) {
        u64 pk = *(const u64*)(&hx[w][l][0]);
        u16* hw = H + (size_t)(t + 1) * 65536 + (size_t)(w * 16 + l) * 1024 + j * 4;
        AS((u64*)hw, pk);
      }
      // this wave's h stores reach L3, then publish this wave's epoch flag
      asm volatile("s_waitcnt vmcnt(0)" ::: "memory");
      if (l == 0) AS(F + j * 128 + w * 32, t + 1);
      // prefetch A1 for t+1 (fills under next step's flag wait + x-proj)
      {
        const u16* apre = A1 + ((size_t)(t + 1) * 64 + arow) * 512 + lk * 8;
        #pragma unroll
        for (int kk = 0; kk < 16; ++kk) ax[kk] = *(const bf16x8*)(apre + kk * 32);
      }
    }
  }
#undef FADDR
#undef WAITV
#undef LD8
#undef MM8
}

extern "C" void kernel_launch(void* const* d_in, const int* in_sizes, int n_in,
                              void* d_out, int out_size, void* d_ws, size_t ws_size,
                              hipStream_t stream) {
  const int*   sent = (const int*)d_in[0];
  const float* emb  = (const float*)d_in[1];
  const float* w_ih = (const float*)d_in[2];
  const float* w_hh = (const float*)d_in[3];
  const float* b_ih = (const float*)d_in[4];
  const float* b_hh = (const float*)d_in[5];
  float* out = (float*)d_out;

  // A1 32Mi | H 512 x 128Ki = 64Mi | F 128Ki  (~96.2 MiB; r15-proven available)
  char* ws = (char*)d_ws;
  u16* A1 = (u16*)ws;
  u16* H  = (u16*)(ws + 33554432);
  int* F  = (int*)(ws + 33554432 + 67108864);

  prep_kernel<<<256, 256, 0, stream>>>((u64*)H, F);
  gather_kernel<<<8192, 256, 0, stream>>>(sent, emb, A1);

  void* args[] = { (void*)&A1, (void*)&w_ih, (void*)&w_hh,
                   (void*)&b_ih, (void*)&b_hh, (void*)&H, (void*)&out, (void*)&F };
  hipError_t err = hipLaunchCooperativeKernel((void*)lstm_kernel, dim3(256), dim3(256),
                                              args, 0, stream);
  if (err != hipSuccess) {
    // dataflow kernel needs co-residency only; 2-blocks/CU envelope on 256 CUs
    lstm_kernel<<<dim3(256), dim3(256), 0, stream>>>(A1, w_ih, w_hh, b_ih, b_hh,
                                                     H, out, F);
  }
}

// Round 18
// 4237.436 us; speedup vs baseline: 1.0095x; 1.0095x over previous
//
#include <hip/hip_runtime.h>

typedef __bf16 bf16x8 __attribute__((ext_vector_type(8)));
typedef float f32x4 __attribute__((ext_vector_type(4)));
typedef unsigned short u16;
typedef unsigned long long u64;

#define NSTEP 512

#define AL(p)   __hip_atomic_load((p), __ATOMIC_RELAXED, __HIP_MEMORY_SCOPE_AGENT)
#define AS(p,v) __hip_atomic_store((p), (v), __ATOMIC_RELAXED, __HIP_MEMORY_SCOPE_AGENT)

__device__ __forceinline__ u16 f2bf(float f) {
  union { float f; unsigned u; } x; x.f = f;
  return (u16)((x.u + 0x7fffu + ((x.u >> 16) & 1u)) >> 16);
}

// zero h buffer 0 + 1024 per-wave epoch flags (every call -> deterministic replays)
__global__ void prep_kernel(u64* __restrict__ H0, int* __restrict__ F) {
  int i = blockIdx.x * blockDim.x + threadIdx.x;
  if (i < 16384) AS(H0 + i, 0ULL);
  if (i < 32768) AS(&F[i], 0);
}

// A1[t*64+b][512] bf16 embedding gather
__global__ void gather_kernel(const int* __restrict__ sent, const float* __restrict__ emb,
                              u16* __restrict__ A1) {
  int row = blockIdx.x * 4 + (threadIdx.x >> 6);   // t*64+b
  int lane = threadIdx.x & 63;
  int t = row >> 6, b = row & 63;
  int idx = sent[b * 512 + t];
  const float* src = emb + (size_t)idx * 512 + lane * 8;
  u16* dst = A1 + (size_t)row * 512 + lane * 8;
  #pragma unroll
  for (int k = 0; k < 8; ++k) dst[k] = f2bf(src[k]);
}

// 256 WGs x 256 thr. WG j owns h cols [j*4,j*4+4), gates packed rb = g*4+nn = lr.
// Weights in padded LDS. h: per-step FRESH buffers — producers store sc1,
// consumers read cached after flag detect (r12/r15-proven). No grid barrier
// (r15); concurrent flag issue (r16). NEW (r18): x-proj split 8+8 so the
// second half covers the chunk-0/1 h fills; 3 independent accumulator chains
// (serial dependent-MFMA chain 48 -> 16).
__global__ void __launch_bounds__(256, 2)
lstm_kernel(const u16* __restrict__ A1,
            const float* __restrict__ wih, const float* __restrict__ whh,
            const float* __restrict__ bih, const float* __restrict__ bhh,
            u16* __restrict__ H, float* __restrict__ out, int* __restrict__ F) {
  __shared__ u16 wlds[48 * 16 * 36];        // 55296 B, stride-36 pad
  __shared__ alignas(8) u16 hx[4][16][4];   // per-wave h-store packing bounce

  const int j   = blockIdx.x;
  const int tid = threadIdx.x;
  const int w   = tid >> 6;            // wave = batch tile 0..3
  const int l   = tid & 63;
  const int lr  = l & 15, lk = l >> 4;
  const int g   = lr >> 2, nn = lr & 3;
  const int wrow = g * 1024 + j * 4 + nn;

  // ---- stage ALL weights fp32->bf16 into padded LDS (once) ----
  for (int task = tid; task < 3072; task += 256) {
    int kk = task >> 6;                 // K chunk of 32 (0..47)
    int rem = task & 63;
    int rb = rem >> 2, q = rem & 3;
    int row = (rb >> 2) * 1024 + j * 4 + (rb & 3);
    const float* src = (kk < 16) ? (wih + (size_t)row * 512 + kk * 32 + q * 8)
                                 : (whh + (size_t)row * 1024 + (kk - 16) * 32 + q * 8);
    u16* dst = wlds + (kk * 16 + rb) * 36 + q * 8;
    #pragma unroll
    for (int e = 0; e < 8; ++e) dst[e] = f2bf(src[e]);
  }
  __syncthreads();

  const float bias = bih[wrow] + bhh[wrow];
  const float sca = (g == 2) ? 2.f : 1.f;   // tanh-as-sigmoid scaling
  const float bd  = (g == 2) ? -1.f : 0.f;
  const int arow = w * 16 + lr;             // batch row for A fragments
  const u16* bx = wlds + lr * 36 + lk * 8;  // + kk*576 per K chunk

  float cst[4] = {0.f, 0.f, 0.f, 0.f};

  // prefetch A1 fragments for t=0
  bf16x8 ax[16];
  {
    const u16* apre = A1 + (size_t)arow * 512 + lk * 8;
    #pragma unroll
    for (int kk = 0; kk < 16; ++kk) ax[kk] = *(const bf16x8*)(apre + kk * 32);
  }

  union AF { bf16x8 v; u64 q[2]; };

  // flag of (producer WG p, wave w) at F[p*128 + w*32]; lane l covers chunk c's
  // producer WG c*64+l.
#define FADDR(c) (F + (((c) * 64 + l) * 128) + w * 32)
#define WAITV(vv, c)                                                        \
  { while (vv < t) { __builtin_amdgcn_s_sleep(1); vv = AL(FADDR(c)); } }
#define LD8(BUF, CH)                                                        \
  { _Pragma("unroll")                                                       \
    for (int r = 0; r < 8; ++r)                                             \
      BUF[r].v = *(const bf16x8*)(hp + (CH) * 256 + r * 32); }
#define MM8(ACC, BUF, W0)                                                   \
  { _Pragma("unroll")                                                       \
    for (int r = 0; r < 8; ++r) {                                           \
      bf16x8 b = *(const bf16x8*)(bx + ((W0) + r) * 576);                   \
      ACC = __builtin_amdgcn_mfma_f32_16x16x32_bf16(BUF[r].v, b, ACC, 0, 0, 0); \
    } }

  #pragma unroll 1
  for (int t = 0; t < NSTEP; ++t) {
    AF ha[8], hb[8];
    const u16* hp = H + (size_t)t * 65536 + (size_t)arow * 1024 + lk * 8;
    // issue ALL 4 chunk-flag loads concurrently
    int v0 = AL(FADDR(0));
    int v1 = AL(FADDR(1));
    int v2 = AL(FADDR(2));
    int v3 = AL(FADDR(3));
    // x-proj first half: covers the flag round trip / publish-detect window
    f32x4 acx = { bias, bias, bias, bias };
    #pragma unroll
    for (int kk = 0; kk < 8; ++kk) {
      bf16x8 b = *(const bf16x8*)(bx + kk * 576);
      acx = __builtin_amdgcn_mfma_f32_16x16x32_bf16(ax[kk], b, acx, 0, 0, 0);
    }
    // detect + issue chunk 0/1 fills ASAP
    WAITV(v0, 0);
    LD8(ha, 0);
    WAITV(v1, 1);
    LD8(hb, 1);
    // x-proj second half covers the ha/hb fills
    #pragma unroll
    for (int kk = 8; kk < 16; ++kk) {
      bf16x8 b = *(const bf16x8*)(bx + kk * 576);
      acx = __builtin_amdgcn_mfma_f32_16x16x32_bf16(ax[kk], b, acx, 0, 0, 0);
    }
    // h-projection: 2 independent chains, waits woven in
    f32x4 ac1 = { 0.f, 0.f, 0.f, 0.f };
    f32x4 ac2 = { 0.f, 0.f, 0.f, 0.f };
    MM8(ac1, ha, 16);
    WAITV(v2, 2);
    LD8(ha, 2);
    MM8(ac2, hb, 24);
    WAITV(v3, 3);
    LD8(hb, 3);
    MM8(ac1, ha, 32);
    MM8(ac2, hb, 40);

    // activations + state update; lanes lr<4 own (rows lk*4+r, col lr)
    float hv4[4], cn4[4];
    #pragma unroll
    for (int r = 0; r < 4; ++r) {
      float xv = acx[r] + ac1[r] + ac2[r];
      float act = sca / (1.f + __expf(-sca * xv)) + bd;  // sigmoid / tanh
      float gg = __shfl_xor(act, 8);
      float ff = __shfl_xor(act, 4);
      float oo = __shfl_xor(act, 12);
      float cn = ff * cst[r] + act * gg;   // act = i at lanes lr<4
      cst[r] = cn;
      float tc = 2.f / (1.f + __expf(-2.f * cn)) - 1.f;
      hv4[r] = oo * tc;
      cn4[r] = cn;
    }

    if (t == NSTEP - 1) {
      if (lr < 4) {
        #pragma unroll
        for (int r = 0; r < 4; ++r) {
          int R = w * 16 + lk * 4 + r;
          out[(size_t)R * 1024 + j * 4 + lr]          = hv4[r];
          out[65536 + (size_t)R * 1024 + j * 4 + lr]  = hv4[r];
          out[131072 + (size_t)R * 1024 + j * 4 + lr] = cn4[r];
        }
      }
    } else {
      // pack wave's 16x4 h tile in LDS (same-wave ds ops in-order; no barrier)
      if (lr < 4) {
        #pragma unroll
        for (int r = 0; r < 4; ++r) hx[w][lk * 4 + r][lr] = f2bf(hv4[r]);
      }
      if (l < 16) {
        u64 pk = *(const u64*)(&hx[w][l][0]);
        u16* hw = H + (size_t)(t + 1) * 65536 + (size_t)(w * 16 + l) * 1024 + j * 4;
        AS((u64*)hw, pk);
      }
      // this wave's h stores reach the coherence point, then publish its flag
      asm volatile("s_waitcnt vmcnt(0)" ::: "memory");
      if (l == 0) AS(F + j * 128 + w * 32, t + 1);
      // prefetch A1 for t+1 (fills under next step's flag wait + x-proj)
      {
        const u16* apre = A1 + ((size_t)(t + 1) * 64 + arow) * 512 + lk * 8;
        #pragma unroll
        for (int kk = 0; kk < 16; ++kk) ax[kk] = *(const bf16x8*)(apre + kk * 32);
      }
    }
  }
#undef FADDR
#undef WAITV
#undef LD8
#undef MM8
}

extern "C" void kernel_launch(void* const* d_in, const int* in_sizes, int n_in,
                              void* d_out, int out_size, void* d_ws, size_t ws_size,
                              hipStream_t stream) {
  const int*   sent = (const int*)d_in[0];
  const float* emb  = (const float*)d_in[1];
  const float* w_ih = (const float*)d_in[2];
  const float* w_hh = (const float*)d_in[3];
  const float* b_ih = (const float*)d_in[4];
  const float* b_hh = (const float*)d_in[5];
  float* out = (float*)d_out;

  // A1 32Mi | H 512 x 128Ki = 64Mi | F 128Ki  (~96.2 MiB; r15-proven available)
  char* ws = (char*)d_ws;
  u16* A1 = (u16*)ws;
  u16* H  = (u16*)(ws + 33554432);
  int* F  = (int*)(ws + 33554432 + 67108864);

  prep_kernel<<<256, 256, 0, stream>>>((u64*)H, F);
  gather_kernel<<<8192, 256, 0, stream>>>(sent, emb, A1);

  void* args[] = { (void*)&A1, (void*)&w_ih, (void*)&w_hh,
                   (void*)&b_ih, (void*)&b_hh, (void*)&H, (void*)&out, (void*)&F };
  hipError_t err = hipLaunchCooperativeKernel((void*)lstm_kernel, dim3(256), dim3(256),
                                              args, 0, stream);
  if (err != hipSuccess) {
    // dataflow kernel needs co-residency only; 2-blocks/CU envelope on 256 CUs
    lstm_kernel<<<dim3(256), dim3(256), 0, stream>>>(A1, w_ih, w_hh, b_ih, b_hh,
                                                     H, out, F);
  }
}